// Round 8
// baseline (30.777 us; speedup 1.0000x reference)
//
#include <hip/hip_runtime.h>

#define SCALE 0.35355339059327379f   // 8^-0.5
#define RSQRT2 0.70710678118654752f

// ws layout (float offsets)
#define PL      4624                 // 68*68 padded plane
#define QP_OFF  0                    // qP[64 oc][68][68]
#define KP_OFF  (64*PL)
#define VP_OFF  (2*64*PL)            // Vpart [4 p][64 x][64 ch]
#define QA_OFF  (VP_OFF + 4*4096)    // qd_acc [oc][il]  (pre-bias/pre-GELU, atomic)
#define KA_OFF  (QA_OFF + 4096)     // kd_acc [oc][il]

// ---------------- K1: 1x1 qkv conv -> planar padded q/k planes + V row-mean partials
//                  + zero the atomic accumulators ----------------
// grid 128: (x = b>>1, yh = b&1), 384 thr = 6 waves: (type q/k/v) x (y-oct), lane = oc.
__global__ __launch_bounds__(384) void k1(const float* __restrict__ f,
                                          const float* __restrict__ w_qkv,
                                          float* __restrict__ ws)
{
    __shared__ float sm[14656];      // wt[64][193] @0 ; fl[64][36] @12352
    const int b = blockIdx.x, t = threadIdx.x;
    const int x = b >> 1, yh = b & 1;
    float* wt = sm;
    float* fl = sm + 12352;

    // zero accumulators: 8192 floats across 128 blocks = 64 per block
    if (t < 64) (ws + QA_OFF)[b*64 + t] = 0.f;

    // zero pad borders: block (x,0) -> qP plane x ; (x,1) -> kP plane x
    {
        float* plane = ws + (yh ? KP_OFF : QP_OFF) + x*PL;
        for (int j = t; j < 528; j += 384) {
            int idx;
            if (j < 272) {
                const int rp = j / 68, c = j % 68;
                const int row = (rp < 2) ? rp : rp + 64;
                idx = row*68 + c;
            } else {
                const int jj = j - 272;
                const int cp = jj >> 6, r2 = (jj & 63) + 2;
                const int col = (cp < 2) ? cp : cp + 64;
                idx = r2*68 + col;
            }
            plane[idx] = 0.f;
        }
    }
    // stage w_qkv transposed: wt[ic][3*64 oc]
    #pragma unroll
    for (int j = 0; j < 8; ++j) {
        const int idx = t + 384*j;   // float4 idx in [0,3072)
        const float4 v = *(const float4*)(w_qkv + 4*idx);
        const int oc = idx >> 4, ic0 = (4*idx) & 63;
        wt[(ic0+0)*193 + oc] = v.x;
        wt[(ic0+1)*193 + oc] = v.y;
        wt[(ic0+2)*193 + oc] = v.z;
        wt[(ic0+3)*193 + oc] = v.w;
    }
    // stage f slab [64 ic][32 y]
    for (int i = t; i < 512; i += 384) {
        const int ic = i >> 3, p = i & 7;
        *(float4*)&fl[ic*36 + p*4] = *(const float4*)(f + ic*4096 + x*64 + yh*32 + p*4);
    }
    __syncthreads();

    const int w = t >> 6, lane = t & 63;
    const int type = w >> 1, yoct = w & 1;
    float acc[16];
    #pragma unroll
    for (int j = 0; j < 16; ++j) acc[j] = 0.f;
    #pragma unroll 4
    for (int ic = 0; ic < 64; ++ic) {
        const float wv = wt[ic*193 + type*64 + lane];
        const float4 p0 = *(const float4*)&fl[ic*36 + yoct*16];
        const float4 p1 = *(const float4*)&fl[ic*36 + yoct*16 + 4];
        const float4 p2 = *(const float4*)&fl[ic*36 + yoct*16 + 8];
        const float4 p3 = *(const float4*)&fl[ic*36 + yoct*16 + 12];
        acc[0]  = fmaf(wv, p0.x, acc[0]);  acc[1]  = fmaf(wv, p0.y, acc[1]);
        acc[2]  = fmaf(wv, p0.z, acc[2]);  acc[3]  = fmaf(wv, p0.w, acc[3]);
        acc[4]  = fmaf(wv, p1.x, acc[4]);  acc[5]  = fmaf(wv, p1.y, acc[5]);
        acc[6]  = fmaf(wv, p1.z, acc[6]);  acc[7]  = fmaf(wv, p1.w, acc[7]);
        acc[8]  = fmaf(wv, p2.x, acc[8]);  acc[9]  = fmaf(wv, p2.y, acc[9]);
        acc[10] = fmaf(wv, p2.z, acc[10]); acc[11] = fmaf(wv, p2.w, acc[11]);
        acc[12] = fmaf(wv, p3.x, acc[12]); acc[13] = fmaf(wv, p3.y, acc[13]);
        acc[14] = fmaf(wv, p3.z, acc[14]); acc[15] = fmaf(wv, p3.w, acc[15]);
    }
    if (type < 2) {
        float* plane = ws + (type ? KP_OFF : QP_OFF) + lane*PL;
        const int base = (x + 2)*68 + yh*32 + yoct*16 + 2;
        #pragma unroll
        for (int j = 0; j < 8; ++j)
            *(float2*)(plane + base + 2*j) = make_float2(acc[2*j], acc[2*j+1]);
    } else {
        float s = 0.f;
        #pragma unroll
        for (int j = 0; j < 16; ++j) s += acc[j];
        (ws + VP_OFF)[(yh*2 + yoct)*4096 + x*64 + lane] = s * 0.015625f;  // /64 partial
    }
}

// ---------------- K2: 11x11 s8 conv as K-split GEMM -> atomicAdd into acc buffers.
// grid 256: (type, ic, khh). 512 thr, lane = il, wave = oc-eighth. No LDS/barriers.
__global__ __launch_bounds__(512) void k2(const float* __restrict__ ws_qP,
                                          const float* __restrict__ ws_kP,
                                          const float* __restrict__ wq,
                                          const float* __restrict__ wk,
                                          float* __restrict__ qa,
                                          float* __restrict__ ka)
{
    const int b = blockIdx.x, t = threadIdx.x;
    const int type = b >> 7, ic = (b >> 1) & 63, khh = b & 1;
    const int kh0 = khh ? 6 : 0, nkh = khh ? 5 : 6;
    const float* plane = (type ? ws_kP : ws_qP) + ic*PL;
    const float* wsrc  = (type ? wk : wq) + ic*121 + kh0*11;
    const int lane = t & 63;
    const int oc0 = __builtin_amdgcn_readfirstlane(t >> 6) * 8;   // wave-uniform
    const int ox = lane >> 3, oy = lane & 7;

    float acc[8] = {0.f,0.f,0.f,0.f,0.f,0.f,0.f,0.f};
    #pragma unroll
    for (int khl = 0; khl < 6; ++khl) {
        if (khl < nkh) {
            const int xp = ox*8 + kh0 + khl;
            const float* prow = plane + xp*68 + oy*8;     // 16B-aligned
            const float4 r0 = *(const float4*)(prow);
            const float4 r1 = *(const float4*)(prow + 4);
            const float4 r2 = *(const float4*)(prow + 8);
            const float pr[12] = {r0.x,r0.y,r0.z,r0.w, r1.x,r1.y,r1.z,r1.w,
                                  r2.x,r2.y,r2.z,r2.w};
            const float* wrow = wsrc + khl*11;
            #pragma unroll
            for (int kw = 0; kw < 11; ++kw) {
                const float pv = pr[kw];
                #pragma unroll
                for (int j = 0; j < 8; ++j) {
                    const float wgt = wrow[(oc0 + j)*7744 + kw];  // uniform -> s_load
                    acc[j] = fmaf(wgt, pv, acc[j]);
                }
            }
        }
    }
    float* ab = (type ? ka : qa) + lane;
    #pragma unroll
    for (int j = 0; j < 8; ++j)
        atomicAdd(ab + (oc0 + j)*64, acc[j]);
}

// ---------------- K3: {Vpart reduce, bias+GELU} prologue + dots + softmax + PV ----------
// grid 64 (x = image row), 512 thr: wave = head, lane = jl.
__global__ __launch_bounds__(512) void k3(const float* __restrict__ qa,
                                          const float* __restrict__ ka,
                                          const float* __restrict__ Vpart,
                                          const float* __restrict__ bq,
                                          const float* __restrict__ bk,
                                          float* __restrict__ out)
{
    __shared__ float vrow[64*65];     // [ch][jl], pitch 65
    __shared__ float kg[4096];        // [oc][jl], post bias+GELU
    const int x = blockIdx.x, t = threadIdx.x;
    for (int idx = t; idx < 4096; idx += 512) {
        const int jl = idx >> 6, ch = idx & 63;
        float s = 0.f;
        #pragma unroll
        for (int p = 0; p < 4; ++p) s += Vpart[p*4096 + jl*64 + ch];
        vrow[ch*65 + jl] = s;
        const int oc = jl, il = ch;   // reuse indices for the kd pass (coalesced)
        const float v = ka[oc*64 + il] + bk[oc];
        kg[oc*64 + il] = 0.5f*v*(1.0f + erff(v*RSQRT2));
    }
    __syncthreads();
    const int h = t >> 6, lane = t & 63;
    float qg[8];
    #pragma unroll
    for (int c = 0; c < 8; ++c) {
        const int oc = h*8 + c;
        const float v = qa[oc*64 + x] + bq[oc];
        qg[c] = 0.5f*v*(1.0f + erff(v*RSQRT2));
    }
    float d = 0.f;
    #pragma unroll
    for (int c = 0; c < 8; ++c)
        d = fmaf(qg[c], kg[(h*8 + c)*64 + lane], d);
    d *= SCALE;
    float m = d;
    #pragma unroll
    for (int mm = 1; mm < 64; mm <<= 1) m = fmaxf(m, __shfl_xor(m, mm, 64));
    const float e = __expf(d - m);
    float ssum = e;
    #pragma unroll
    for (int mm = 1; mm < 64; mm <<= 1) ssum += __shfl_xor(ssum, mm, 64);
    const float p = e / ssum;
    #pragma unroll
    for (int c = 0; c < 8; ++c) {
        float r = p * vrow[(h*8 + c)*65 + lane];
        #pragma unroll
        for (int mm = 1; mm < 64; mm <<= 1) r += __shfl_xor(r, mm, 64);
        out[(h*8 + c)*4096 + x*64 + lane] = r;
    }
}

extern "C" void kernel_launch(void* const* d_in, const int* in_sizes, int n_in,
                              void* d_out, int out_size, void* d_ws, size_t ws_size,
                              hipStream_t stream) {
    const float* f     = (const float*)d_in[0];
    const float* w_qkv = (const float*)d_in[1];
    const float* wq    = (const float*)d_in[2];
    const float* bq    = (const float*)d_in[3];
    const float* wk    = (const float*)d_in[4];
    const float* bk    = (const float*)d_in[5];
    float* out = (float*)d_out;
    float* ws  = (float*)d_ws;

    k1<<<128, 384, 0, stream>>>(f, w_qkv, ws);
    k2<<<256, 512, 0, stream>>>(ws + QP_OFF, ws + KP_OFF, wq, wk,
                                ws + QA_OFF, ws + KA_OFF);
    k3<<<64, 512, 0, stream>>>(ws + QA_OFF, ws + KA_OFF, ws + VP_OFF,
                               bq, bk, out);
}